// Round 1
// baseline (21604.762 us; speedup 1.0000x reference)
//
#include <hip/hip_runtime.h>
#include <stdint.h>

#define B_TRAJ 4096
#define H_DIM  100
#define T_STEPS 100
#define WID    256
#define ROWS   16
#define NBLK   (B_TRAJ / ROWS)   // 256 blocks

__device__ __forceinline__ uint32_t rotl32(uint32_t v, int d) {
  return (v << d) | (v >> (32 - d));
}

// JAX Threefry-2x32, 20 rounds (5 groups of 4), exact key schedule.
__device__ __forceinline__ void threefry2x32(uint32_t k0, uint32_t k1,
                                             uint32_t x0, uint32_t x1,
                                             uint32_t& o0, uint32_t& o1) {
  const uint32_t k2 = k0 ^ k1 ^ 0x1BD11BDAu;
  x0 += k0; x1 += k1;
  x0 += x1; x1 = rotl32(x1, 13); x1 ^= x0;
  x0 += x1; x1 = rotl32(x1, 15); x1 ^= x0;
  x0 += x1; x1 = rotl32(x1, 26); x1 ^= x0;
  x0 += x1; x1 = rotl32(x1,  6); x1 ^= x0;
  x0 += k1; x1 += k2 + 1u;
  x0 += x1; x1 = rotl32(x1, 17); x1 ^= x0;
  x0 += x1; x1 = rotl32(x1, 29); x1 ^= x0;
  x0 += x1; x1 = rotl32(x1, 16); x1 ^= x0;
  x0 += x1; x1 = rotl32(x1, 24); x1 ^= x0;
  x0 += k2; x1 += k0 + 2u;
  x0 += x1; x1 = rotl32(x1, 13); x1 ^= x0;
  x0 += x1; x1 = rotl32(x1, 15); x1 ^= x0;
  x0 += x1; x1 = rotl32(x1, 26); x1 ^= x0;
  x0 += x1; x1 = rotl32(x1,  6); x1 ^= x0;
  x0 += k0; x1 += k1 + 3u;
  x0 += x1; x1 = rotl32(x1, 17); x1 ^= x0;
  x0 += x1; x1 = rotl32(x1, 29); x1 ^= x0;
  x0 += x1; x1 = rotl32(x1, 16); x1 ^= x0;
  x0 += x1; x1 = rotl32(x1, 24); x1 ^= x0;
  x0 += k1; x1 += k2 + 4u;
  x0 += x1; x1 = rotl32(x1, 13); x1 ^= x0;
  x0 += x1; x1 = rotl32(x1, 15); x1 ^= x0;
  x0 += x1; x1 = rotl32(x1, 26); x1 ^= x0;
  x0 += x1; x1 = rotl32(x1,  6); x1 ^= x0;
  x0 += k2; x1 += k0 + 5u;
  o0 = x0; o1 = x1;
}

// XLA ErfInv32 (Giles), matches lax.erf_inv for f32.
__device__ __forceinline__ float erfinv_f32(float x) {
  float w = -log1pf(-x * x);
  float p;
  if (w < 5.0f) {
    w = w - 2.5f;
    p = 2.81022636e-08f;
    p = fmaf(p, w, 3.43273939e-07f);
    p = fmaf(p, w, -3.5233877e-06f);
    p = fmaf(p, w, -4.39150654e-06f);
    p = fmaf(p, w, 0.00021858087f);
    p = fmaf(p, w, -0.00125372503f);
    p = fmaf(p, w, -0.00417768164f);
    p = fmaf(p, w, 0.246640727f);
    p = fmaf(p, w, 1.50140941f);
  } else {
    w = sqrtf(w) - 3.0f;
    p = -0.000200214257f;
    p = fmaf(p, w, 0.000100950558f);
    p = fmaf(p, w, 0.00134934322f);
    p = fmaf(p, w, -0.00367342844f);
    p = fmaf(p, w, 0.00573950773f);
    p = fmaf(p, w, -0.0076224613f);
    p = fmaf(p, w, 0.00943887047f);
    p = fmaf(p, w, 1.00167406f);
    p = fmaf(p, w, 2.83297682f);
  }
  return p * x;
}

// Forward 256->256 layer: thread t owns output column t for all 16 rows.
// LDS reads are uniform-address across the block (pure broadcast, no conflicts).
__device__ __forceinline__ uint32_t fwd256(int t, const float* __restrict__ Wl,
                                           const float* __restrict__ bl,
                                           float (*in)[WID], float (*out)[WID]) {
  float acc[ROWS];
  const float bias = bl[t];
#pragma unroll
  for (int r = 0; r < ROWS; ++r) acc[r] = bias;
  const float* wr = Wl + t * WID;
  for (int k = 0; k < WID; k += 4) {
    const float4 w = *reinterpret_cast<const float4*>(wr + k);
#pragma unroll
    for (int r = 0; r < ROWS; ++r) {
      const float4 a = *reinterpret_cast<const float4*>(&in[r][k]);
      acc[r] = fmaf(a.x, w.x, acc[r]);
      acc[r] = fmaf(a.y, w.y, acc[r]);
      acc[r] = fmaf(a.z, w.z, acc[r]);
      acc[r] = fmaf(a.w, w.w, acc[r]);
    }
  }
  uint32_t m = 0;
#pragma unroll
  for (int r = 0; r < ROWS; ++r) {
    const float v = acc[r];
    if (v > 0.0f) m |= (1u << r);
    out[r][t] = fmaxf(v, 0.0f);
  }
  return m;
}

// Backward: da[k=t] = sum_j W[j][t] * dp[j]; apply this layer's relu mask.
__device__ __forceinline__ void bwd256(int t, const float* __restrict__ Wl,
                                       uint32_t mask, float (*dpin)[WID],
                                       float (*dpout)[WID]) {
  float acc[ROWS];
#pragma unroll
  for (int r = 0; r < ROWS; ++r) acc[r] = 0.0f;
  for (int j = 0; j < WID; j += 4) {
    const float w0 = Wl[(j + 0) * WID + t];
    const float w1 = Wl[(j + 1) * WID + t];
    const float w2 = Wl[(j + 2) * WID + t];
    const float w3 = Wl[(j + 3) * WID + t];
#pragma unroll
    for (int r = 0; r < ROWS; ++r) {
      const float4 d = *reinterpret_cast<const float4*>(&dpin[r][j]);
      acc[r] = fmaf(d.x, w0, acc[r]);
      acc[r] = fmaf(d.y, w1, acc[r]);
      acc[r] = fmaf(d.z, w2, acc[r]);
      acc[r] = fmaf(d.w, w3, acc[r]);
    }
  }
#pragma unroll
  for (int r = 0; r < ROWS; ++r)
    dpout[r][t] = ((mask >> r) & 1u) ? acc[r] : 0.0f;
}

// Full MLP fwd + input-grad (VJP). Updates y_s, z_s; optionally writes ys.
__device__ void mlp_eval(int tid, float t_val,
                         const float* __restrict__ W0, const float* __restrict__ b0,
                         const float* __restrict__ W1, const float* __restrict__ b1,
                         const float* __restrict__ W2, const float* __restrict__ b2,
                         const float* __restrict__ W3, const float* __restrict__ b3,
                         const float* __restrict__ W4, const float* __restrict__ b4,
                         float (*bufA)[WID], float (*bufB)[WID],
                         float* x_s, float* z_s, float* y_s,
                         float* ys_out, int row0) {
  const int t = tid;
  // build input a0 = [t, x] into bufA[r][0..100]
  if (tid < ROWS) bufA[tid][0] = t_val;
  for (int e = tid; e < ROWS * H_DIM; e += 256) {
    const int r = e / H_DIM, h = e - r * H_DIM;
    bufA[r][1 + h] = x_s[e];
  }
  __syncthreads();

  uint32_t m1, m2, m3, m4;

  // L0: 101 -> 256 (scalar k loop; W0 rows are 101 floats, unaligned for float4)
  {
    float acc[ROWS];
    const float bias = b0[t];
#pragma unroll
    for (int r = 0; r < ROWS; ++r) acc[r] = bias;
    const float* wr = W0 + t * 101;
    for (int k = 0; k < 101; ++k) {
      const float w = wr[k];
#pragma unroll
      for (int r = 0; r < ROWS; ++r) acc[r] = fmaf(bufA[r][k], w, acc[r]);
    }
    uint32_t m = 0;
#pragma unroll
    for (int r = 0; r < ROWS; ++r) {
      const float v = acc[r];
      if (v > 0.0f) m |= (1u << r);
      bufB[r][t] = fmaxf(v, 0.0f);
    }
    m1 = m;
  }
  __syncthreads();

  m2 = fwd256(t, W1, b1, bufB, bufA);  // a2 -> bufA
  __syncthreads();
  m3 = fwd256(t, W2, b2, bufA, bufB);  // a3 -> bufB
  __syncthreads();
  m4 = fwd256(t, W3, b3, bufB, bufA);  // a4 -> bufA
  __syncthreads();

  // y = W4 a4 + b4 (16 lanes per row) ; dp4 = W4 .* mask4 -> bufB
  {
    const int g = tid >> 4, li = tid & 15;
    float part = 0.0f;
#pragma unroll
    for (int mm = 0; mm < 16; ++mm) {
      const int j = li + (mm << 4);
      part += W4[j] * bufA[g][j];
    }
#pragma unroll
    for (int off = 8; off >= 1; off >>= 1) part += __shfl_xor(part, off, 16);
    if (li == 0) {
      const float yv = part + b4[0];
      y_s[g] = yv;
      if (ys_out) ys_out[row0 + g] = yv;
    }
    const float w4t = W4[t];
#pragma unroll
    for (int r = 0; r < ROWS; ++r)
      bufB[r][t] = ((m4 >> r) & 1u) ? w4t : 0.0f;
  }
  __syncthreads();

  bwd256(t, W3, m3, bufB, bufA);  // dp3 -> bufA
  __syncthreads();
  bwd256(t, W2, m2, bufA, bufB);  // dp2 -> bufB
  __syncthreads();
  bwd256(t, W1, m1, bufB, bufA);  // dp1 -> bufA
  __syncthreads();

  // z[h] = sum_j W0[j][1+h] * dp1[j]  (threads 1..100 own columns 1..100)
  if (t >= 1 && t <= H_DIM) {
    float acc[ROWS];
#pragma unroll
    for (int r = 0; r < ROWS; ++r) acc[r] = 0.0f;
    for (int j = 0; j < WID; j += 4) {
      const float w0 = W0[(j + 0) * 101 + t];
      const float w1 = W0[(j + 1) * 101 + t];
      const float w2 = W0[(j + 2) * 101 + t];
      const float w3 = W0[(j + 3) * 101 + t];
#pragma unroll
      for (int r = 0; r < ROWS; ++r) {
        const float4 d = *reinterpret_cast<const float4*>(&bufA[r][j]);
        acc[r] = fmaf(d.x, w0, acc[r]);
        acc[r] = fmaf(d.y, w1, acc[r]);
        acc[r] = fmaf(d.z, w2, acc[r]);
        acc[r] = fmaf(d.w, w3, acc[r]);
      }
    }
#pragma unroll
    for (int r = 0; r < ROWS; ++r) z_s[r * H_DIM + (t - 1)] = acc[r];
  }
  __syncthreads();
}

__global__ __launch_bounds__(256, 1) void fbsde_kernel(
    const float* __restrict__ x0, const float* __restrict__ t0p,
    const float* __restrict__ dtp,
    const float* __restrict__ W0, const float* __restrict__ b0,
    const float* __restrict__ W1, const float* __restrict__ b1,
    const float* __restrict__ W2, const float* __restrict__ b2,
    const float* __restrict__ W3, const float* __restrict__ b3,
    const float* __restrict__ W4, const float* __restrict__ b4,
    float* __restrict__ out) {
  __shared__ __align__(16) float bufA[ROWS][WID];
  __shared__ __align__(16) float bufB[ROWS][WID];
  __shared__ float x_s[ROWS * H_DIM];
  __shared__ float z_s[ROWS * H_DIM];
  __shared__ float dw_s[ROWS * H_DIM];
  __shared__ float y_s[ROWS];
  __shared__ uint32_t keyA[T_STEPS], keyB[T_STEPS];

  const int tid = threadIdx.x;
  const int blk = blockIdx.x;
  const int row0 = blk * ROWS;

  // Key chain: k0 = key(42); per step: child0 = block(0,0) (use), child1 = block(0,1) (carry).
  // (JAX threefry_partitionable foldlike split.)
  if (tid == 0) {
    uint32_t c0 = 0u, c1 = 42u;
    for (int s = 0; s < T_STEPS; ++s) {
      uint32_t a0_, a1_, n0, n1;
      threefry2x32(c0, c1, 0u, 0u, a0_, a1_);
      threefry2x32(c0, c1, 0u, 1u, n0, n1);
      keyA[s] = a0_; keyB[s] = a1_;
      c0 = n0; c1 = n1;
    }
  }
  for (int e = tid; e < ROWS * H_DIM; e += 256)
    x_s[e] = x0[row0 * H_DIM + e];
  const float t0v = t0p[0];
  const float dtv = dtp[0];
  const float sqdt = sqrtf(dtv);
  __syncthreads();

  float* const out_xfin = out;                                  // (B,H)
  float* const out_yfin = out + 409600;                         // (B,1)
  float* const out_zfin = out + 413696;                         // (B,H)
  float* const out_xs   = out + 823296;                         // (T,B,H)
  float* const out_yt   = out + 823296 + 40960000;              // (T,B,1)
  float* const out_ys   = out + 823296 + 40960000 + 409600;     // (T,B,1)

  // initial evaluation at t = 0
  mlp_eval(tid, 0.0f, W0, b0, W1, b1, W2, b2, W3, b3, W4, b4,
           bufA, bufB, x_s, z_s, y_s, nullptr, row0);

  for (int s = 0; s < T_STEPS; ++s) {
    // dW: partitionable random_bits = lane0 ^ lane1 of block (0, flat_index)
    const uint32_t ka = keyA[s], kb = keyB[s];
    for (int e = tid; e < ROWS * H_DIM; e += 256) {
      const uint32_t f = (uint32_t)(blk * (ROWS * H_DIM) + e);
      uint32_t o0, o1;
      threefry2x32(ka, kb, 0u, f, o0, o1);
      const uint32_t bits = o0 ^ o1;
      const float fr = __uint_as_float((bits >> 9) | 0x3F800000u) - 1.0f;
      const float minv = -0.99999994f;  // nextafter(-1, 0)
      const float u = fmaxf(fr * 2.0f + minv, minv);
      const float n = 1.41421354f * erfinv_f32(u);
      dw_s[e] = n * sqdt;
    }
    __syncthreads();

    // SDE row sums: phi = 0.05*(y - sum(x*z)); y_tilde = y + phi*dt + sum(z*sig*dW)
    {
      const int g = tid >> 4, li = tid & 15;
      float s1 = 0.0f, s2 = 0.0f;
      for (int h = li; h < H_DIM; h += 16) {
        const float xv = x_s[g * H_DIM + h];
        const float zv = z_s[g * H_DIM + h];
        const float dw = dw_s[g * H_DIM + h];
        s1 += xv * zv;
        s2 += (zv * (0.4f * xv)) * dw;
      }
#pragma unroll
      for (int off = 8; off >= 1; off >>= 1) {
        s1 += __shfl_xor(s1, off, 16);
        s2 += __shfl_xor(s2, off, 16);
      }
      if (li == 0) {
        const float yv = y_s[g];
        const float phi = 0.05f * (yv - s1);
        out_yt[(size_t)s * B_TRAJ + row0 + g] = yv + phi * dtv + s2;
      }
    }
    __syncthreads();

    // x update + write xs
    for (int e = tid; e < ROWS * H_DIM; e += 256) {
      const float xv = x_s[e];
      const float x1 = xv + (0.4f * xv) * dw_s[e];
      x_s[e] = x1;
      out_xs[(size_t)s * (B_TRAJ * H_DIM) + (size_t)row0 * H_DIM + e] = x1;
    }
    __syncthreads();

    const float tv = t0v + (float)(s + 1) * dtv;
    mlp_eval(tid, tv, W0, b0, W1, b1, W2, b2, W3, b3, W4, b4,
             bufA, bufB, x_s, z_s, y_s, out_ys + (size_t)s * B_TRAJ, row0);
  }

  // finals: carry (x, y, z)
  for (int e = tid; e < ROWS * H_DIM; e += 256) {
    out_xfin[(size_t)row0 * H_DIM + e] = x_s[e];
    out_zfin[(size_t)row0 * H_DIM + e] = z_s[e];
  }
  if (tid < ROWS) out_yfin[row0 + tid] = y_s[tid];
}

extern "C" void kernel_launch(void* const* d_in, const int* in_sizes, int n_in,
                              void* d_out, int out_size, void* d_ws, size_t ws_size,
                              hipStream_t stream) {
  (void)in_sizes; (void)n_in; (void)d_ws; (void)ws_size; (void)out_size;
  const float* x0 = (const float*)d_in[0];
  const float* t0 = (const float*)d_in[1];
  const float* dt = (const float*)d_in[2];
  // d_in[3] = num_timesteps (fixed 100; output layout depends on it)
  const float* W0 = (const float*)d_in[4];
  const float* b0 = (const float*)d_in[5];
  const float* W1 = (const float*)d_in[6];
  const float* b1 = (const float*)d_in[7];
  const float* W2 = (const float*)d_in[8];
  const float* b2 = (const float*)d_in[9];
  const float* W3 = (const float*)d_in[10];
  const float* b3 = (const float*)d_in[11];
  const float* W4 = (const float*)d_in[12];
  const float* b4 = (const float*)d_in[13];
  float* out = (float*)d_out;

  hipLaunchKernelGGL(fbsde_kernel, dim3(NBLK), dim3(256), 0, stream,
                     x0, t0, dt, W0, b0, W1, b1, W2, b2, W3, b3, W4, b4, out);
}

// Round 2
// 1993.088 us; speedup vs baseline: 10.8398x; 10.8398x over previous
//
#include <hip/hip_runtime.h>
#include <stdint.h>

#define B_TRAJ  4096
#define H_DIM   100
#define T_STEPS 100
#define WID     256
#define ROWS    16
#define NBLK    256
#define THREADS 512

typedef float  f32x4  __attribute__((ext_vector_type(4)));
typedef __bf16 bf16x8 __attribute__((ext_vector_type(8)));

// ---- packed-weight layout in d_ws (ushort/bf16 elements) ----
// flat idx within a pack = (kt*N + n)*32 + kk ; kk = g*8 + e
#define OFF_P0F 0        // [4 ][256][32]  B[k][n] = W0[n][k], K=128 pad (real 101)
#define OFF_P1F 32768    // [8 ][256][32]  B[k][n] = W1[n][k]
#define OFF_P2F 98304
#define OFF_P3F 163840
#define OFF_P1B 229376   // [8 ][256][32]  B[k][n] = W1[k][n]
#define OFF_P2B 294912
#define OFF_P3B 360448
#define OFF_P0B 425984   // [8 ][128][32]  B[k][h] = W0[k][1+h], N=128 pad (real 100)
#define PACK_TOTAL 458752

__device__ __forceinline__ uint16_t f2bf(float f) {
  uint32_t u = __float_as_uint(f);
  uint32_t r = u + 0x7FFFu + ((u >> 16) & 1u);   // round-to-nearest-even
  return (uint16_t)(r >> 16);
}
__device__ __forceinline__ float bf2f(uint16_t u) {
  return __uint_as_float(((uint32_t)u) << 16);
}

__device__ __forceinline__ uint32_t rotl32(uint32_t v, int d) {
  return (v << d) | (v >> (32 - d));
}

// JAX Threefry-2x32, 20 rounds, exact key schedule.
__device__ __forceinline__ void threefry2x32(uint32_t k0, uint32_t k1,
                                             uint32_t x0, uint32_t x1,
                                             uint32_t& o0, uint32_t& o1) {
  const uint32_t k2 = k0 ^ k1 ^ 0x1BD11BDAu;
  x0 += k0; x1 += k1;
  x0 += x1; x1 = rotl32(x1, 13); x1 ^= x0;
  x0 += x1; x1 = rotl32(x1, 15); x1 ^= x0;
  x0 += x1; x1 = rotl32(x1, 26); x1 ^= x0;
  x0 += x1; x1 = rotl32(x1,  6); x1 ^= x0;
  x0 += k1; x1 += k2 + 1u;
  x0 += x1; x1 = rotl32(x1, 17); x1 ^= x0;
  x0 += x1; x1 = rotl32(x1, 29); x1 ^= x0;
  x0 += x1; x1 = rotl32(x1, 16); x1 ^= x0;
  x0 += x1; x1 = rotl32(x1, 24); x1 ^= x0;
  x0 += k2; x1 += k0 + 2u;
  x0 += x1; x1 = rotl32(x1, 13); x1 ^= x0;
  x0 += x1; x1 = rotl32(x1, 15); x1 ^= x0;
  x0 += x1; x1 = rotl32(x1, 26); x1 ^= x0;
  x0 += x1; x1 = rotl32(x1,  6); x1 ^= x0;
  x0 += k0; x1 += k1 + 3u;
  x0 += x1; x1 = rotl32(x1, 17); x1 ^= x0;
  x0 += x1; x1 = rotl32(x1, 29); x1 ^= x0;
  x0 += x1; x1 = rotl32(x1, 16); x1 ^= x0;
  x0 += x1; x1 = rotl32(x1, 24); x1 ^= x0;
  x0 += k1; x1 += k2 + 4u;
  x0 += x1; x1 = rotl32(x1, 13); x1 ^= x0;
  x0 += x1; x1 = rotl32(x1, 15); x1 ^= x0;
  x0 += x1; x1 = rotl32(x1, 26); x1 ^= x0;
  x0 += x1; x1 = rotl32(x1,  6); x1 ^= x0;
  x0 += k2; x1 += k0 + 5u;
  o0 = x0; o1 = x1;
}

// XLA ErfInv32 (Giles)
__device__ __forceinline__ float erfinv_f32(float x) {
  float w = -log1pf(-x * x);
  float p;
  if (w < 5.0f) {
    w = w - 2.5f;
    p = 2.81022636e-08f;
    p = fmaf(p, w, 3.43273939e-07f);
    p = fmaf(p, w, -3.5233877e-06f);
    p = fmaf(p, w, -4.39150654e-06f);
    p = fmaf(p, w, 0.00021858087f);
    p = fmaf(p, w, -0.00125372503f);
    p = fmaf(p, w, -0.00417768164f);
    p = fmaf(p, w, 0.246640727f);
    p = fmaf(p, w, 1.50140941f);
  } else {
    w = sqrtf(w) - 3.0f;
    p = -0.000200214257f;
    p = fmaf(p, w, 0.000100950558f);
    p = fmaf(p, w, 0.00134934322f);
    p = fmaf(p, w, -0.00367342844f);
    p = fmaf(p, w, 0.00573950773f);
    p = fmaf(p, w, -0.0076224613f);
    p = fmaf(p, w, 0.00943887047f);
    p = fmaf(p, w, 1.00167406f);
    p = fmaf(p, w, 2.83297682f);
  }
  return p * x;
}

// ---------------- weight packing (once per launch, ~0.9 MB) ----------------
__global__ __launch_bounds__(256) void pack_kernel(
    const float* __restrict__ W0, const float* __restrict__ W1,
    const float* __restrict__ W2, const float* __restrict__ W3,
    uint16_t* __restrict__ P) {
  const int i = blockIdx.x * 256 + threadIdx.x;
  if (i >= PACK_TOTAL) return;
  float v;
  if (i < OFF_P1F) {                 // P0F
    int e = i - OFF_P0F;
    int kk = e & 31, n = (e >> 5) & 255, kt = e >> 13;
    int k = kt * 32 + kk;
    v = (k < 101) ? W0[n * 101 + k] : 0.0f;
  } else if (i < OFF_P2F) {          // P1F
    int e = i - OFF_P1F;
    int kk = e & 31, n = (e >> 5) & 255, kt = e >> 13;
    v = W1[n * 256 + kt * 32 + kk];
  } else if (i < OFF_P3F) {          // P2F
    int e = i - OFF_P2F;
    int kk = e & 31, n = (e >> 5) & 255, kt = e >> 13;
    v = W2[n * 256 + kt * 32 + kk];
  } else if (i < OFF_P1B) {          // P3F
    int e = i - OFF_P3F;
    int kk = e & 31, n = (e >> 5) & 255, kt = e >> 13;
    v = W3[n * 256 + kt * 32 + kk];
  } else if (i < OFF_P2B) {          // P1B
    int e = i - OFF_P1B;
    int kk = e & 31, n = (e >> 5) & 255, kt = e >> 13;
    v = W1[(kt * 32 + kk) * 256 + n];
  } else if (i < OFF_P3B) {          // P2B
    int e = i - OFF_P2B;
    int kk = e & 31, n = (e >> 5) & 255, kt = e >> 13;
    v = W2[(kt * 32 + kk) * 256 + n];
  } else if (i < OFF_P0B) {          // P3B
    int e = i - OFF_P3B;
    int kk = e & 31, n = (e >> 5) & 255, kt = e >> 13;
    v = W3[(kt * 32 + kk) * 256 + n];
  } else {                           // P0B
    int e = i - OFF_P0B;
    int kk = e & 31, n = (e >> 5) & 127, kt = e >> 12;
    int k = kt * 32 + kk;
    v = (n < 100) ? W0[k * 101 + 1 + n] : 0.0f;
  }
  P[i] = f2bf(v);
}

// ---------------- MFMA GEMM pieces ----------------
// D[r][c]: r = (lane>>4)*4 + reg, c = (lane&15) + 16*ntile  [m89-verified]
// A[r][k-slot]: r = lane&15 ; B[k-slot][c]: c = lane&15. k-slot order cancels
// between A and B because both use the same (g,e) packing.

template<int KT, int INS>
__device__ __forceinline__ void gemm_fwd(const uint16_t (*in)[INS],
                                         const uint16_t* __restrict__ P,
                                         const float* __restrict__ bias,
                                         uint16_t (*outb)[264],
                                         int wave, int lane) {
  const int row16 = lane & 15, g = lane >> 4;
  const int c0 = row16 + 16 * (wave * 2 + 0);
  const int c1 = row16 + 16 * (wave * 2 + 1);
  const float bv0 = bias[c0], bv1 = bias[c1];
  f32x4 acc0 = {bv0, bv0, bv0, bv0};
  f32x4 acc1 = {bv1, bv1, bv1, bv1};
#pragma unroll
  for (int kt = 0; kt < KT; ++kt) {
    bf16x8 a  = *reinterpret_cast<const bf16x8*>(&in[row16][kt * 32 + g * 8]);
    bf16x8 b0 = *reinterpret_cast<const bf16x8*>(&P[(kt * 256 + c0) * 32 + g * 8]);
    bf16x8 b1 = *reinterpret_cast<const bf16x8*>(&P[(kt * 256 + c1) * 32 + g * 8]);
    acc0 = __builtin_amdgcn_mfma_f32_16x16x32_bf16(a, b0, acc0, 0, 0, 0);
    acc1 = __builtin_amdgcn_mfma_f32_16x16x32_bf16(a, b1, acc1, 0, 0, 0);
  }
#pragma unroll
  for (int reg = 0; reg < 4; ++reg) {
    const int r = g * 4 + reg;
    outb[r][c0] = f2bf(fmaxf(acc0[reg], 0.0f));
    outb[r][c1] = f2bf(fmaxf(acc1[reg], 0.0f));
  }
}

// dp_out = (dp_in @ P) .* (mact != 0)
__device__ __forceinline__ void gemm_bwd(const uint16_t (*in)[264],
                                         const uint16_t* __restrict__ P,
                                         const uint16_t (*mact)[264],
                                         uint16_t (*outb)[264],
                                         int wave, int lane) {
  const int row16 = lane & 15, g = lane >> 4;
  const int c0 = row16 + 16 * (wave * 2 + 0);
  const int c1 = row16 + 16 * (wave * 2 + 1);
  f32x4 acc0 = {0.f, 0.f, 0.f, 0.f};
  f32x4 acc1 = {0.f, 0.f, 0.f, 0.f};
#pragma unroll
  for (int kt = 0; kt < 8; ++kt) {
    bf16x8 a  = *reinterpret_cast<const bf16x8*>(&in[row16][kt * 32 + g * 8]);
    bf16x8 b0 = *reinterpret_cast<const bf16x8*>(&P[(kt * 256 + c0) * 32 + g * 8]);
    bf16x8 b1 = *reinterpret_cast<const bf16x8*>(&P[(kt * 256 + c1) * 32 + g * 8]);
    acc0 = __builtin_amdgcn_mfma_f32_16x16x32_bf16(a, b0, acc0, 0, 0, 0);
    acc1 = __builtin_amdgcn_mfma_f32_16x16x32_bf16(a, b1, acc1, 0, 0, 0);
  }
#pragma unroll
  for (int reg = 0; reg < 4; ++reg) {
    const int r = g * 4 + reg;
    outb[r][c0] = mact[r][c0] ? f2bf(acc0[reg]) : (uint16_t)0;
    outb[r][c1] = mact[r][c1] ? f2bf(acc1[reg]) : (uint16_t)0;
  }
}

// z = dp1 @ P0B ; N=128 (cols<100 valid), output fp32 to z_s
__device__ __forceinline__ void gemm_bwd0(const uint16_t (*in)[264],
                                          const uint16_t* __restrict__ P,
                                          float* __restrict__ z_s,
                                          int wave, int lane) {
  const int row16 = lane & 15, g = lane >> 4;
  const int c = row16 + 16 * wave;   // 0..127
  f32x4 acc = {0.f, 0.f, 0.f, 0.f};
#pragma unroll
  for (int kt = 0; kt < 8; ++kt) {
    bf16x8 a = *reinterpret_cast<const bf16x8*>(&in[row16][kt * 32 + g * 8]);
    bf16x8 b = *reinterpret_cast<const bf16x8*>(&P[(kt * 128 + c) * 32 + g * 8]);
    acc = __builtin_amdgcn_mfma_f32_16x16x32_bf16(a, b, acc, 0, 0, 0);
  }
  if (c < H_DIM) {
#pragma unroll
    for (int reg = 0; reg < 4; ++reg)
      z_s[(g * 4 + reg) * H_DIM + c] = acc[reg];
  }
}

// ---------------- main kernel ----------------
struct SmemT {
  uint16_t actI[ROWS][136];   // MLP input, K padded to 128
  uint16_t act1[ROWS][264];
  uint16_t act2[ROWS][264];
  uint16_t act3[ROWS][264];
  uint16_t act4[ROWS][264];
  uint16_t dpA[ROWS][264];
  uint16_t dpB[ROWS][264];
  float x_s[ROWS * H_DIM];
  float z_s[ROWS * H_DIM];
  float dw_s[ROWS * H_DIM];
  float y_s[ROWS];
  uint32_t keyA[T_STEPS], keyB[T_STEPS];
};

__device__ void mlp_eval(SmemT& sm, int tid, float t_val,
                         const uint16_t* __restrict__ P,
                         const float* __restrict__ b0, const float* __restrict__ b1,
                         const float* __restrict__ b2, const float* __restrict__ b3,
                         const float* __restrict__ W4, const float* __restrict__ b4,
                         float* __restrict__ ys_out, int row0) {
  const int wave = tid >> 6, lane = tid & 63;

  // build input: [t, x, 0-pad]
  const uint16_t tbf = f2bf(t_val);
  for (int e = tid; e < ROWS * 128; e += THREADS) {
    const int r = e >> 7, c = e & 127;
    uint16_t v;
    if (c == 0) v = tbf;
    else if (c <= H_DIM) v = f2bf(sm.x_s[r * H_DIM + c - 1]);
    else v = 0;
    sm.actI[r][c] = v;
  }
  __syncthreads();

  gemm_fwd<4, 136>(sm.actI, P + OFF_P0F, b0, sm.act1, wave, lane);
  __syncthreads();
  gemm_fwd<8, 264>(sm.act1, P + OFF_P1F, b1, sm.act2, wave, lane);
  __syncthreads();
  gemm_fwd<8, 264>(sm.act2, P + OFF_P2F, b2, sm.act3, wave, lane);
  __syncthreads();
  gemm_fwd<8, 264>(sm.act3, P + OFF_P3F, b3, sm.act4, wave, lane);
  __syncthreads();

  // y = act4 @ W4 + b4 ; dp4 = (act4!=0) * W4
  {
    const int t = tid & 255;
    const int rbase = (tid >> 8) * 8;
    const uint16_t w4u = f2bf(W4[t]);
#pragma unroll
    for (int r = 0; r < 8; ++r)
      sm.dpA[rbase + r][t] = sm.act4[rbase + r][t] ? w4u : (uint16_t)0;
  }
  {
    const int gr = tid >> 5, li = tid & 31;
    float s = 0.0f;
#pragma unroll
    for (int m = 0; m < 8; ++m) {
      const int j = li + (m << 5);
      s += bf2f(sm.act4[gr][j]) * W4[j];
    }
#pragma unroll
    for (int off = 16; off >= 1; off >>= 1) s += __shfl_xor(s, off, 32);
    if (li == 0) {
      const float yv = s + b4[0];
      sm.y_s[gr] = yv;
      if (ys_out) ys_out[row0 + gr] = yv;
    }
  }
  __syncthreads();

  gemm_bwd(sm.dpA, P + OFF_P3B, sm.act3, sm.dpB, wave, lane);
  __syncthreads();
  gemm_bwd(sm.dpB, P + OFF_P2B, sm.act2, sm.dpA, wave, lane);
  __syncthreads();
  gemm_bwd(sm.dpA, P + OFF_P1B, sm.act1, sm.dpB, wave, lane);
  __syncthreads();
  gemm_bwd0(sm.dpB, P + OFF_P0B, sm.z_s, wave, lane);
  __syncthreads();
}

__global__ __launch_bounds__(THREADS, 1) void fbsde_kernel(
    const float* __restrict__ x0, const float* __restrict__ t0p,
    const float* __restrict__ dtp,
    const float* __restrict__ b0, const float* __restrict__ b1,
    const float* __restrict__ b2, const float* __restrict__ b3,
    const float* __restrict__ W4, const float* __restrict__ b4,
    const uint16_t* __restrict__ P, float* __restrict__ out) {
  __shared__ __align__(16) SmemT sm;

  const int tid = threadIdx.x;
  const int blk = blockIdx.x;
  const int row0 = blk * ROWS;

  if (tid == 0) {
    uint32_t c0 = 0u, c1 = 42u;
    for (int s = 0; s < T_STEPS; ++s) {
      uint32_t a0_, a1_, n0, n1;
      threefry2x32(c0, c1, 0u, 0u, a0_, a1_);
      threefry2x32(c0, c1, 0u, 1u, n0, n1);
      sm.keyA[s] = a0_; sm.keyB[s] = a1_;
      c0 = n0; c1 = n1;
    }
  }
  for (int e = tid; e < ROWS * H_DIM; e += THREADS)
    sm.x_s[e] = x0[row0 * H_DIM + e];
  const float t0v = t0p[0];
  const float dtv = dtp[0];
  const float sqdt = sqrtf(dtv);
  __syncthreads();

  float* const out_xfin = out;                                  // (B,H)
  float* const out_yfin = out + 409600;                         // (B,1)
  float* const out_zfin = out + 413696;                         // (B,H)
  float* const out_xs   = out + 823296;                         // (T,B,H)
  float* const out_yt   = out + 823296 + 40960000;              // (T,B,1)
  float* const out_ys   = out + 823296 + 40960000 + 409600;     // (T,B,1)

  mlp_eval(sm, tid, 0.0f, P, b0, b1, b2, b3, W4, b4, nullptr, row0);

  for (int s = 0; s < T_STEPS; ++s) {
    const uint32_t ka = sm.keyA[s], kb = sm.keyB[s];
    for (int e = tid; e < ROWS * H_DIM; e += THREADS) {
      const uint32_t f = (uint32_t)(blk * (ROWS * H_DIM) + e);
      uint32_t o0, o1;
      threefry2x32(ka, kb, 0u, f, o0, o1);
      const uint32_t bits = o0 ^ o1;
      const float fr = __uint_as_float((bits >> 9) | 0x3F800000u) - 1.0f;
      const float minv = -0.99999994f;  // nextafter(-1, 0)
      const float u = fmaxf(fr * 2.0f + minv, minv);
      const float n = 1.41421354f * erfinv_f32(u);
      sm.dw_s[e] = n * sqdt;
    }
    __syncthreads();

    // phi/y_tilde row sums (32 lanes per row)
    {
      const int g = tid >> 5, li = tid & 31;
      float s1 = 0.0f, s2 = 0.0f;
      for (int h = li; h < H_DIM; h += 32) {
        const float xv = sm.x_s[g * H_DIM + h];
        const float zv = sm.z_s[g * H_DIM + h];
        const float dw = sm.dw_s[g * H_DIM + h];
        s1 += xv * zv;
        s2 += (zv * (0.4f * xv)) * dw;
      }
#pragma unroll
      for (int off = 16; off >= 1; off >>= 1) {
        s1 += __shfl_xor(s1, off, 32);
        s2 += __shfl_xor(s2, off, 32);
      }
      if (li == 0) {
        const float yv = sm.y_s[g];
        const float phi = 0.05f * (yv - s1);
        out_yt[(size_t)s * B_TRAJ + row0 + g] = yv + phi * dtv + s2;
      }
    }
    __syncthreads();

    for (int e = tid; e < ROWS * H_DIM; e += THREADS) {
      const float xv = sm.x_s[e];
      const float x1 = xv + (0.4f * xv) * sm.dw_s[e];
      sm.x_s[e] = x1;
      out_xs[(size_t)s * (B_TRAJ * H_DIM) + (size_t)row0 * H_DIM + e] = x1;
    }
    __syncthreads();

    const float tv = t0v + (float)(s + 1) * dtv;
    mlp_eval(sm, tid, tv, P, b0, b1, b2, b3, W4, b4,
             out_ys + (size_t)s * B_TRAJ, row0);
  }

  for (int e = tid; e < ROWS * H_DIM; e += THREADS) {
    out_xfin[(size_t)row0 * H_DIM + e] = sm.x_s[e];
    out_zfin[(size_t)row0 * H_DIM + e] = sm.z_s[e];
  }
  if (tid < ROWS) out_yfin[row0 + tid] = sm.y_s[tid];
}

extern "C" void kernel_launch(void* const* d_in, const int* in_sizes, int n_in,
                              void* d_out, int out_size, void* d_ws, size_t ws_size,
                              hipStream_t stream) {
  (void)in_sizes; (void)n_in; (void)ws_size; (void)out_size;
  const float* x0 = (const float*)d_in[0];
  const float* t0 = (const float*)d_in[1];
  const float* dt = (const float*)d_in[2];
  const float* W0 = (const float*)d_in[4];
  const float* b0 = (const float*)d_in[5];
  const float* W1 = (const float*)d_in[6];
  const float* b1 = (const float*)d_in[7];
  const float* W2 = (const float*)d_in[8];
  const float* b2 = (const float*)d_in[9];
  const float* W3 = (const float*)d_in[10];
  const float* b3 = (const float*)d_in[11];
  const float* W4 = (const float*)d_in[12];
  const float* b4 = (const float*)d_in[13];
  uint16_t* P = (uint16_t*)d_ws;
  float* out = (float*)d_out;

  hipLaunchKernelGGL(pack_kernel, dim3((PACK_TOTAL + 255) / 256), dim3(256), 0,
                     stream, W0, W1, W2, W3, P);
  hipLaunchKernelGGL(fbsde_kernel, dim3(NBLK), dim3(THREADS), 0, stream,
                     x0, t0, dt, b0, b1, b2, b3, W4, b4, P, out);
}